// Round 7
// baseline (332.785 us; speedup 1.0000x reference)
//
#include <hip/hip_runtime.h>
#include <math.h>

#define NNODES 200000
#define NG 1000
#define NPG 200
#define KNN 5
#define MD 128
#define S6 (1.0f / 6.0f)
#define HS_WORDS 26624  // 208 rows x 128 words, unified swizzled addressing

typedef short short8 __attribute__((ext_vector_type(8)));
typedef float floatx4 __attribute__((ext_vector_type(4)));

// RNE bf16 split-pack: returns (bf16(v) << 16) | bf16(v - bf16(v))
__device__ __forceinline__ unsigned splitpack(float f) {
  unsigned u = __float_as_uint(f);
  unsigned hb = (u + 0x7fffu + ((u >> 16) & 1u)) >> 16;
  float hf = __uint_as_float(hb << 16);
  float r = f - hf;
  unsigned v = __float_as_uint(r);
  unsigned lb = (v + 0x7fffu + ((v >> 16) & 1u)) >> 16;
  return (hb << 16) | (lb & 0xffffu);
}

__device__ __forceinline__ void unpack8(int4 u, int4 v, short8* hi, short8* lo) {
  unsigned w[8] = {(unsigned)u.x, (unsigned)u.y, (unsigned)u.z, (unsigned)u.w,
                   (unsigned)v.x, (unsigned)v.y, (unsigned)v.z, (unsigned)v.w};
  short8 h, l;
#pragma unroll
  for (int i = 0; i < 8; i++) {
    h[i] = (short)(w[i] >> 16);
    l[i] = (short)(w[i] & 0xffffu);
  }
  *hi = h;
  *lo = l;
}

// Unified swizzled addressing: value (row, col) lives at word
//   row*128 + (((col>>2) ^ (row&7)) << 2) + (col&3)
// Same mapping for fp32 h and packed split-bf16 x -> in-place column-group
// conversion. XOR keeps each granule inside its 8-granule block.
__device__ __forceinline__ float4 rd4(const float* Hs, int row, int kq) {
  return *(const float4*)(Hs + row * MD + ((kq ^ (row & 7)) << 2));
}

// ---------------- kNN: one block per graph (validated) — LOCAL ids ----------------
__global__ __launch_bounds__(256) void knn_kernel(const float* __restrict__ pos,
                                                  int* __restrict__ knn) {
  __shared__ float sp[NPG * 3];
  int g = blockIdx.x;
  int t = threadIdx.x;
  for (int i = t; i < NPG * 3; i += 256) sp[i] = pos[(size_t)g * NPG * 3 + i];
  __syncthreads();
  if (t < NPG) {
    float x = sp[t * 3 + 0], y = sp[t * 3 + 1], z = sp[t * 3 + 2];
    float bd[KNN];
    int bi[KNN];
#pragma unroll
    for (int k = 0; k < KNN; k++) { bd[k] = 3.0e38f; bi[k] = 0; }
    for (int j = 0; j < NPG; j++) {
      if (j == t) continue;
      float dx = __fsub_rn(x, sp[j * 3 + 0]);
      float dy = __fsub_rn(y, sp[j * 3 + 1]);
      float dz = __fsub_rn(z, sp[j * 3 + 2]);
      float d2 = __fadd_rn(__fadd_rn(__fmul_rn(dx, dx), __fmul_rn(dy, dy)),
                           __fmul_rn(dz, dz));
      if (d2 < bd[KNN - 1]) {
        bd[KNN - 1] = d2; bi[KNN - 1] = j;
#pragma unroll
        for (int k = KNN - 1; k > 0; k--) {
          if (bd[k] < bd[k - 1]) {
            float td = bd[k]; bd[k] = bd[k - 1]; bd[k - 1] = td;
            int ti = bi[k]; bi[k] = bi[k - 1]; bi[k - 1] = ti;
          }
        }
      }
    }
#pragma unroll
    for (int k = 0; k < KNN; k++)
      knn[((size_t)g * NPG + t) * KNN + k] = bi[k];  // local id within graph
  }
}

// ---------------- merged: embW0 = emb @ W0 (blocks 0..49) + W1/W2 prepack
// (blocks 50..65) — independent, one launch saves a dispatch gap ----------------
__global__ __launch_bounds__(256) void emb_prepack_kernel(
    const float* __restrict__ emb, const float* __restrict__ convW,
    float* __restrict__ embW, unsigned short* __restrict__ WhiF,
    unsigned short* __restrict__ WloF) {
  int b = blockIdx.x;
  int t = threadIdx.x;
  if (b < 50) {
    int idx = b * 256 + t;  // 12800 total
    int r = idx >> 7, c = idx & 127;
    const float* W = convW;
    float a = 0.0f;
    for (int k = 0; k < MD; k++) a += emb[r * MD + k] * W[k * MD + c];
    embW[idx] = a;
  } else {
    int idx = (b - 50) * 256 + t;  // 0..4095
    int lane = idx & 63;
    int c = (idx >> 6) & 3;
    int T = (idx >> 8) & 7;
    int l = idx >> 11;  // 0..1 -> W1, W2
    const float* W = convW + (size_t)(l + 1) * MD * MD;
    int m = lane & 15, q = lane >> 4;
    int n = 16 * T + m;
    unsigned short hi[8], lo[8];
#pragma unroll
    for (int j = 0; j < 8; j++) {
      int k = 32 * c + 8 * q + j;
      unsigned p = splitpack(W[(size_t)k * MD + n]);
      hi[j] = (unsigned short)(p >> 16);
      lo[j] = (unsigned short)(p & 0xffffu);
    }
    *(short8*)(WhiF + (size_t)idx * 8) = *(short8*)hi;
    *(short8*)(WloF + (size_t)idx * 8) = *(short8*)lo;
  }
}

// ---------------- fused per-graph megakernel ----------------
// One block = one graph, 1024 threads (16 waves), 1 block/CU (LDS-limited).
// R6 lesson: residual conflicts ~70% from A-frag reads (8 extra cy per b128
// with 8 distinct-addr lanes/bank-window — intrinsic to the shape, swizzle-
// invariant). Fix: cut COUNT 8x. Wave wv owns row-tile wv (13 tiles of 16
// rows), loops ALL 8 col-tiles: A read once per k-chunk (8 b128/wave/layer),
// B streamed from L2 (VMEM pipe, not LDS). acc[8] = 32 VGPRs.
__global__ __launch_bounds__(1024)
__attribute__((amdgpu_waves_per_eu(4, 4))) void fused_kernel(
    const int* __restrict__ z, const int* __restrict__ knn,
    const float* __restrict__ embW, const float* __restrict__ convb,
    const unsigned short* __restrict__ WhiF, const unsigned short* __restrict__ WloF,
    const float* __restrict__ rW1, const float* __restrict__ rb1,
    const float* __restrict__ rW2, const float* __restrict__ rb2,
    const float* __restrict__ rW3, const float* __restrict__ rb3,
    float* __restrict__ out) {
  __shared__ float Hs[HS_WORDS];   // 106,496 B
  __shared__ int kl[NPG * KNN];    // 4,000 B
  __shared__ float red[8 * MD];    // 4,096 B
  __shared__ float pooled[MD];
  __shared__ float h1s[64];
  __shared__ float h2s[32];

  const int g = blockIdx.x;
  const int t = threadIdx.x;

  if (t < 250) ((int4*)kl)[t] = ((const int4*)(knn + (size_t)g * NPG * KNN))[t];

  const int rs = t >> 3;   // row slot 0..127 (8 lanes per row)
  const int g0 = t & 7;    // granule slot within 8-block

  // ---- stage h0 = embW[z] (fp32, unified addressing; 8 lanes/row) ----
  __syncthreads();  // kl visible
#pragma unroll
  for (int ps = 0; ps < 2; ps++) {
    const int row = 128 * ps + rs;
    if (row < NPG) {
      const int zi = z[g * NPG + row];
      const float4* E = (const float4*)(embW + (size_t)zi * MD);
      const int sw = row & 7;
#pragma unroll
      for (int j = 0; j < 4; j++) {
        const int kq = g0 + 8 * j;
        *(float4*)(Hs + row * MD + ((kq ^ sw) << 2)) = E[kq];
      }
    }
  }
  __syncthreads();

  const int lane = t & 63;
  const int wv = t >> 6;
  const int m = lane & 15;
  const int q = lane >> 4;

#pragma unroll 1
  for (int l = 0; l < 2; l++) {
    const float* bb = convb + l * MD;
    // ---- agg + bias + relu + pack, IN PLACE, 2 column phases x 2 passes ----
#pragma unroll 1
    for (int ph = 0; ph < 2; ph++) {
      int4 pkv[2][2];  // [pass][j] — 16 regs live across ONE barrier
#pragma unroll
      for (int ps = 0; ps < 2; ps++) {
        const int row = 128 * ps + rs;
        if (row < NPG) {
          const int* kn = kl + row * KNN;
          const int i1 = kn[0], i2 = kn[1], i3 = kn[2], i4 = kn[3], i5 = kn[4];
#pragma unroll
          for (int j = 0; j < 2; j++) {
            const int kq = g0 + 8 * j + 16 * ph;
            float4 s = rd4(Hs, row, kq);
            float4 a1 = rd4(Hs, i1, kq); s.x += a1.x; s.y += a1.y; s.z += a1.z; s.w += a1.w;
            float4 a2 = rd4(Hs, i2, kq); s.x += a2.x; s.y += a2.y; s.z += a2.z; s.w += a2.w;
            float4 a3 = rd4(Hs, i3, kq); s.x += a3.x; s.y += a3.y; s.z += a3.z; s.w += a3.w;
            float4 a4 = rd4(Hs, i4, kq); s.x += a4.x; s.y += a4.y; s.z += a4.z; s.w += a4.w;
            float4 a5 = rd4(Hs, i5, kq); s.x += a5.x; s.y += a5.y; s.z += a5.z; s.w += a5.w;
            const float4 bv = ((const float4*)bb)[kq];
            pkv[ps][j].x = (int)splitpack(fmaxf(s.x * S6 + bv.x, 0.0f));
            pkv[ps][j].y = (int)splitpack(fmaxf(s.y * S6 + bv.y, 0.0f));
            pkv[ps][j].z = (int)splitpack(fmaxf(s.z * S6 + bv.z, 0.0f));
            pkv[ps][j].w = (int)splitpack(fmaxf(s.w * S6 + bv.w, 0.0f));
          }
        }
      }
      __syncthreads();  // ALL reads (both passes) done before in-place writes
      unsigned* Hu = (unsigned*)Hs;
#pragma unroll
      for (int ps = 0; ps < 2; ps++) {
        const int row = 128 * ps + rs;
        if (row < NPG) {
          const int sw = row & 7;
#pragma unroll
          for (int j = 0; j < 2; j++) {
            const int kq = g0 + 8 * j + 16 * ph;
            *(int4*)(Hu + row * MD + ((kq ^ sw) << 2)) = pkv[ps][j];
          }
        }
      }
      __syncthreads();  // packed writes visible
    }

    // ---- MFMA: h_{l+1} = x @ W_{l+1} (split-bf16 3-product) ----
    // Wave wv (0..12) owns row-tile wv; loops all 8 col-tiles. A-frags read
    // ONCE per k-chunk; B streamed from L2 (frag-ordered, coalesced 16B/lane).
    const unsigned short* Wh = WhiF + (size_t)l * 16384;
    const unsigned short* Wl_ = WloF + (size_t)l * 16384;
    floatx4 acc[8];
#pragma unroll
    for (int T = 0; T < 8; T++) acc[T] = (floatx4){0.f, 0.f, 0.f, 0.f};
    if (wv < 13) {
      const int swm = m & 7;  // row&7 == m&7 (16*wv multiple of 8... 16wv%8==0)
      const unsigned* abase = (const unsigned*)Hs + (16 * wv + m) * MD;
#pragma unroll
      for (int c = 0; c < 4; c++) {
        const int g1 = (2 * q + 8 * c) ^ swm;
        const int g2 = (2 * q + 8 * c + 1) ^ swm;
        // rows 200..207 (wv=12) read garbage: row-confined in MFMA, discarded
        int4 u = *(const int4*)(abase + (g1 << 2));
        int4 v = *(const int4*)(abase + (g2 << 2));
        short8 ahi, alo;
        unpack8(u, v, &ahi, &alo);
#pragma unroll
        for (int T = 0; T < 8; T++) {
          const size_t off = ((size_t)(T * 4 + c) * 64 + lane) * 8;
          short8 bhi = *(const short8*)(Wh + off);
          short8 blo = *(const short8*)(Wl_ + off);
          acc[T] = __builtin_amdgcn_mfma_f32_16x16x32_bf16(ahi, bhi, acc[T], 0, 0, 0);
          acc[T] = __builtin_amdgcn_mfma_f32_16x16x32_bf16(ahi, blo, acc[T], 0, 0, 0);
          acc[T] = __builtin_amdgcn_mfma_f32_16x16x32_bf16(alo, bhi, acc[T], 0, 0, 0);
        }
      }
    }
    __syncthreads();  // all packed-x frag reads done before overwrite

    // ---- write-back h_{l+1} (fp32, unified addressing) ----
    if (wv < 13) {
      const int cw = m & 3;
#pragma unroll
      for (int T = 0; T < 8; T++) {
        const int colg = 4 * T + (m >> 2);  // (16*T+m)>>2
#pragma unroll
        for (int reg = 0; reg < 4; reg++) {
          const int row = 16 * wv + 4 * q + reg;
          if (row < NPG)
            Hs[row * MD + ((colg ^ (row & 7)) << 2) + cw] = acc[T][reg];
        }
      }
    }
    __syncthreads();
  }

  // ---- tail: x3 = relu(S6*agg(h2) + b2), in place, same shape ----
  {
    const float* bb = convb + 2 * MD;
#pragma unroll 1
    for (int ph = 0; ph < 2; ph++) {
      float4 xv[2][2];  // 16 regs live across ONE barrier
#pragma unroll
      for (int ps = 0; ps < 2; ps++) {
        const int row = 128 * ps + rs;
        if (row < NPG) {
          const int* kn = kl + row * KNN;
          const int i1 = kn[0], i2 = kn[1], i3 = kn[2], i4 = kn[3], i5 = kn[4];
#pragma unroll
          for (int j = 0; j < 2; j++) {
            const int kq = g0 + 8 * j + 16 * ph;
            float4 s = rd4(Hs, row, kq);
            float4 a1 = rd4(Hs, i1, kq); s.x += a1.x; s.y += a1.y; s.z += a1.z; s.w += a1.w;
            float4 a2 = rd4(Hs, i2, kq); s.x += a2.x; s.y += a2.y; s.z += a2.z; s.w += a2.w;
            float4 a3 = rd4(Hs, i3, kq); s.x += a3.x; s.y += a3.y; s.z += a3.z; s.w += a3.w;
            float4 a4 = rd4(Hs, i4, kq); s.x += a4.x; s.y += a4.y; s.z += a4.z; s.w += a4.w;
            float4 a5 = rd4(Hs, i5, kq); s.x += a5.x; s.y += a5.y; s.z += a5.z; s.w += a5.w;
            const float4 bv = ((const float4*)bb)[kq];
            xv[ps][j].x = fmaxf(s.x * S6 + bv.x, 0.0f);
            xv[ps][j].y = fmaxf(s.y * S6 + bv.y, 0.0f);
            xv[ps][j].z = fmaxf(s.z * S6 + bv.z, 0.0f);
            xv[ps][j].w = fmaxf(s.w * S6 + bv.w, 0.0f);
          }
        }
      }
      __syncthreads();
#pragma unroll
      for (int ps = 0; ps < 2; ps++) {
        const int row = 128 * ps + rs;
        if (row < NPG) {
          const int sw = row & 7;
#pragma unroll
          for (int j = 0; j < 2; j++) {
            const int kq = g0 + 8 * j + 16 * ph;
            *(float4*)(Hs + row * MD + ((kq ^ sw) << 2)) = xv[ps][j];
          }
        }
      }
      __syncthreads();
    }
  }

  // ---- mean pool: 8 row-groups x 128 cols (unified addressing reads) ----
  {
    const int col = t & 127;
    const int j = t >> 7;  // 0..7, rows j*25..j*25+24
    const int colg = col >> 2, cw = col & 3;
    float s = 0.f;
    for (int i = 0; i < 25; i++) {
      const int row = j * 25 + i;
      s += Hs[row * MD + ((colg ^ (row & 7)) << 2) + cw];
    }
    red[j * MD + col] = s;
  }
  __syncthreads();
  if (t < MD) {
    float p = 0.f;
#pragma unroll
    for (int j = 0; j < 8; j++) p += red[j * MD + t];
    pooled[t] = p * (1.0f / (float)NPG);
  }
  __syncthreads();

  // ---- regressor MLP ----
  if (t < 64) {
    float a = rb1[t];
    for (int c = 0; c < 128; c++) a += pooled[c] * rW1[c * 64 + t];
    h1s[t] = fmaxf(a, 0.0f);
  }
  __syncthreads();
  if (t < 32) {
    float a = rb2[t];
    for (int c = 0; c < 64; c++) a += h1s[c] * rW2[c * 32 + t];
    h2s[t] = fmaxf(a, 0.0f);
  }
  __syncthreads();
  if (t == 0) {
    float a = rb3[0];
    for (int c = 0; c < 32; c++) a += h2s[c] * rW3[c];
    out[g] = a;
  }
}

extern "C" void kernel_launch(void* const* d_in, const int* in_sizes, int n_in,
                              void* d_out, int out_size, void* d_ws, size_t ws_size,
                              hipStream_t stream) {
  const int* z = (const int*)d_in[0];
  const float* pos = (const float*)d_in[1];
  const float* emb = (const float*)d_in[3];
  const float* convW = (const float*)d_in[4];  // [3][128][128]
  const float* convb = (const float*)d_in[5];  // [3][128]
  const float* rW1 = (const float*)d_in[6];
  const float* rb1 = (const float*)d_in[7];
  const float* rW2 = (const float*)d_in[8];
  const float* rb2 = (const float*)d_in[9];
  const float* rW3 = (const float*)d_in[10];
  const float* rb3 = (const float*)d_in[11];
  float* out = (float*)d_out;

  char* ws = (char*)d_ws;
  int* knn = (int*)ws;                                      // 4,000,000 B
  float* embW = (float*)(ws + 4000000);                     // 51,200 B
  unsigned short* WhiF = (unsigned short*)(ws + 4051200);   // 65,536 B
  unsigned short* WloF = WhiF + 32768;                      // 65,536 B

  knn_kernel<<<NG, 256, 0, stream>>>(pos, knn);
  emb_prepack_kernel<<<66, 256, 0, stream>>>(emb, convW, embW, WhiF, WloF);
  fused_kernel<<<NG, 1024, 0, stream>>>(z, knn, embW, convb, WhiF, WloF,
                                        rW1, rb1, rW2, rb2, rW3, rb3, out);
}

// Round 8
// 269.699 us; speedup vs baseline: 1.2339x; 1.2339x over previous
//
#include <hip/hip_runtime.h>
#include <math.h>

#define NNODES 200000
#define NG 1000
#define NPG 200
#define KNN 5
#define MD 128
#define S6 (1.0f / 6.0f)
#define HS_WORDS 26624  // 208 rows x 128 words, unified swizzled addressing

typedef short short8 __attribute__((ext_vector_type(8)));
typedef float floatx4 __attribute__((ext_vector_type(4)));

// RNE bf16 split-pack: returns (bf16(v) << 16) | bf16(v - bf16(v))
__device__ __forceinline__ unsigned splitpack(float f) {
  unsigned u = __float_as_uint(f);
  unsigned hb = (u + 0x7fffu + ((u >> 16) & 1u)) >> 16;
  float hf = __uint_as_float(hb << 16);
  float r = f - hf;
  unsigned v = __float_as_uint(r);
  unsigned lb = (v + 0x7fffu + ((v >> 16) & 1u)) >> 16;
  return (hb << 16) | (lb & 0xffffu);
}

__device__ __forceinline__ void unpack8(int4 u, int4 v, short8* hi, short8* lo) {
  unsigned w[8] = {(unsigned)u.x, (unsigned)u.y, (unsigned)u.z, (unsigned)u.w,
                   (unsigned)v.x, (unsigned)v.y, (unsigned)v.z, (unsigned)v.w};
  short8 h, l;
#pragma unroll
  for (int i = 0; i < 8; i++) {
    h[i] = (short)(w[i] >> 16);
    l[i] = (short)(w[i] & 0xffffu);
  }
  *hi = h;
  *lo = l;
}

// Unified swizzled addressing: value (row, col) lives at word
//   row*128 + (((col>>2) ^ (row&7)) << 2) + (col&3)
__device__ __forceinline__ float4 rd4(const float* Hs, int row, int kq) {
  return *(const float4*)(Hs + row * MD + ((kq ^ (row & 7)) << 2));
}

// ---------------- merged pre-kernel ----------------
// blocks 0..199: embW0 = emb @ W0, 4-way k-split + LDS reduce (R7 lesson:
//   old version was 200 waves chip-wide, latency-bound serial k-loop).
// blocks 200..215: W1/W2 prepack into MFMA B-frag layout (validated).
__global__ __launch_bounds__(256) void emb_prepack_kernel(
    const float* __restrict__ emb, const float* __restrict__ convW,
    float* __restrict__ embW, unsigned short* __restrict__ WhiF,
    unsigned short* __restrict__ WloF) {
  __shared__ float part[256];
  const int b = blockIdx.x;
  const int t = threadIdx.x;
  if (b < 200) {
    const int o = b * 64 + (t >> 2);  // output 0..12799
    const int r = o >> 7, c = o & 127;
    const int ks = t & 3;             // k-chunk 32*ks..+31
    const float* er = emb + (size_t)r * MD + 32 * ks;
    const float* wc = convW + c + (size_t)(32 * ks) * MD;
    float a = 0.0f;
#pragma unroll
    for (int k = 0; k < 32; k++) a += er[k] * wc[(size_t)k * MD];
    part[t] = a;
    __syncthreads();
    if (t < 64) {
      embW[b * 64 + t] =
          part[4 * t] + part[4 * t + 1] + part[4 * t + 2] + part[4 * t + 3];
    }
  } else {
    const int idx = (b - 200) * 256 + t;  // 0..4095
    const int lane = idx & 63;
    const int c = (idx >> 6) & 3;
    const int T = (idx >> 8) & 7;
    const int l = idx >> 11;  // 0..1 -> W1, W2
    const float* W = convW + (size_t)(l + 1) * MD * MD;
    const int m = lane & 15, q = lane >> 4;
    const int n = 16 * T + m;
    unsigned short hi[8], lo[8];
#pragma unroll
    for (int j = 0; j < 8; j++) {
      const int k = 32 * c + 8 * q + j;
      const unsigned p = splitpack(W[(size_t)k * MD + n]);
      hi[j] = (unsigned short)(p >> 16);
      lo[j] = (unsigned short)(p & 0xffffu);
    }
    *(short8*)(WhiF + (size_t)idx * 8) = *(short8*)hi;
    *(short8*)(WloF + (size_t)idx * 8) = *(short8*)lo;
  }
}

// ---------------- fused per-graph megakernel (kNN folded in) ----------------
// One block = one graph, 1024 threads (16 waves), 1 block/CU (LDS-limited).
// Iron law (R2/R3/R7): allocator pins 64 VGPR at 1024 threads; no phase may
// exceed ~60 live regs, no reg array lives across >1 barrier.
// Prologue computes kNN in-block: 200 rows x 5 partitions x 40 candidates,
// reg-held top-5 (strict <, identical semantics to validated knn_kernel),
// partial lists staged in Hs scratch, 5-way sorted merge with NAMED head
// registers (no runtime-indexed local arrays). Removes the knn launch and
// its 8 MB HBM round-trip. Main body = R6's validated structure verbatim.
__global__ __launch_bounds__(1024)
__attribute__((amdgpu_waves_per_eu(4, 4))) void fused_kernel(
    const int* __restrict__ z, const float* __restrict__ pos,
    const float* __restrict__ embW, const float* __restrict__ convb,
    const unsigned short* __restrict__ WhiF, const unsigned short* __restrict__ WloF,
    const float* __restrict__ rW1, const float* __restrict__ rb1,
    const float* __restrict__ rW2, const float* __restrict__ rb2,
    const float* __restrict__ rW3, const float* __restrict__ rb3,
    float* __restrict__ out) {
  __shared__ float Hs[HS_WORDS];   // 106,496 B (also kNN candidate scratch)
  __shared__ int kl[NPG * KNN];    // 4,000 B
  __shared__ float sp[NPG * 3];    // 2,400 B (positions)
  __shared__ float red[8 * MD];    // 4,096 B
  __shared__ float pooled[MD];
  __shared__ float h1s[64];
  __shared__ float h2s[32];

  const int g = blockIdx.x;
  const int t = threadIdx.x;

  // ---- kNN prologue: load positions ----
  if (t < NPG * 3) sp[t] = pos[(size_t)g * NPG * 3 + t];
  __syncthreads();

  // ---- kNN partial top-5: row r5 = t/5, partition p5 = t%5 (j in [40p5,40p5+40)) ----
  if (t < NPG * 5) {
    const int r5 = t / 5;
    const int p5 = t - 5 * r5;
    const float x = sp[r5 * 3 + 0], y = sp[r5 * 3 + 1], zz = sp[r5 * 3 + 2];
    float bd[KNN];
    int bi[KNN];
#pragma unroll
    for (int k = 0; k < KNN; k++) { bd[k] = 3.0e38f; bi[k] = 0; }
    const int j0 = 40 * p5;
    for (int j = j0; j < j0 + 40; j++) {
      if (j == r5) continue;
      const float dx = __fsub_rn(x, sp[j * 3 + 0]);
      const float dy = __fsub_rn(y, sp[j * 3 + 1]);
      const float dz = __fsub_rn(zz, sp[j * 3 + 2]);
      const float d2 = __fadd_rn(__fadd_rn(__fmul_rn(dx, dx), __fmul_rn(dy, dy)),
                                 __fmul_rn(dz, dz));
      if (d2 < bd[KNN - 1]) {
        bd[KNN - 1] = d2; bi[KNN - 1] = j;
#pragma unroll
        for (int k = KNN - 1; k > 0; k--) {
          if (bd[k] < bd[k - 1]) {
            const float td = bd[k]; bd[k] = bd[k - 1]; bd[k - 1] = td;
            const int ti = bi[k]; bi[k] = bi[k - 1]; bi[k - 1] = ti;
          }
        }
      }
    }
    // stage sorted partial list in Hs scratch
    float* cd = Hs;                       // [1000][5] d2
    int* ci = (int*)Hs + 8192;            // [1000][5] idx
#pragma unroll
    for (int k = 0; k < KNN; k++) { cd[t * 5 + k] = bd[k]; ci[t * 5 + k] = bi[k]; }
  }
  __syncthreads();

  // ---- kNN merge: 5-way sorted merge per row (named heads, no arrays) ----
  if (t < NPG) {
    const float* cdr = Hs + t * 25;
    const int* cir = (const int*)Hs + 8192 + t * 25;
    int h0 = 0, h1 = 0, h2 = 0, h3 = 0, h4 = 0;
#pragma unroll
    for (int k = 0; k < KNN; k++) {
      const float INFV = 3.2e38f;
      const float c0 = (h0 < 5) ? cdr[0 + h0] : INFV;
      const float c1 = (h1 < 5) ? cdr[5 + h1] : INFV;
      const float c2 = (h2 < 5) ? cdr[10 + h2] : INFV;
      const float c3 = (h3 < 5) ? cdr[15 + h3] : INFV;
      const float c4 = (h4 < 5) ? cdr[20 + h4] : INFV;
      float best = c0;
      int bp = 0;
      if (c1 < best) { best = c1; bp = 1; }
      if (c2 < best) { best = c2; bp = 2; }
      if (c3 < best) { best = c3; bp = 3; }
      if (c4 < best) { best = c4; bp = 4; }
      const int hb = bp == 0 ? h0 : bp == 1 ? h1 : bp == 2 ? h2 : bp == 3 ? h3 : h4;
      kl[t * 5 + k] = cir[bp * 5 + hb];
      h0 += (bp == 0); h1 += (bp == 1); h2 += (bp == 2);
      h3 += (bp == 3); h4 += (bp == 4);
    }
  }
  __syncthreads();

  const int rs = t >> 3;   // row slot 0..127 (8 lanes per row)
  const int g0 = t & 7;    // granule slot within 8-block

  // ---- stage h0 = embW[z] (fp32, unified addressing; 8 lanes/row) ----
#pragma unroll
  for (int ps = 0; ps < 2; ps++) {
    const int row = 128 * ps + rs;
    if (row < NPG) {
      const int zi = z[g * NPG + row];
      const float4* E = (const float4*)(embW + (size_t)zi * MD);
      const int sw = row & 7;
#pragma unroll
      for (int j = 0; j < 4; j++) {
        const int kq = g0 + 8 * j;
        *(float4*)(Hs + row * MD + ((kq ^ sw) << 2)) = E[kq];
      }
    }
  }
  __syncthreads();

  const int lane = t & 63;
  const int wv = t >> 6;
  const int m = lane & 15;
  const int q = lane >> 4;
  const int Tc = wv & 7;   // col-tile owned by this wave
  const int hg = wv >> 3;  // row-tile group: 0 -> tiles 0..6, 1 -> tiles 7..12
  const int nrt = hg ? 6 : 7;
  const int rt0 = hg ? 7 : 0;

#pragma unroll 1
  for (int l = 0; l < 2; l++) {
    const float* bb = convb + l * MD;
    // ---- agg + bias + relu + pack, IN PLACE, 2 column phases x 2 passes ----
#pragma unroll 1
    for (int ph = 0; ph < 2; ph++) {
      int4 pkv[2][2];  // [pass][j] — 16 regs live across ONE barrier
#pragma unroll
      for (int ps = 0; ps < 2; ps++) {
        const int row = 128 * ps + rs;
        if (row < NPG) {
          const int* kn = kl + row * KNN;
          const int i1 = kn[0], i2 = kn[1], i3 = kn[2], i4 = kn[3], i5 = kn[4];
#pragma unroll
          for (int j = 0; j < 2; j++) {
            const int kq = g0 + 8 * j + 16 * ph;
            float4 s = rd4(Hs, row, kq);
            float4 a1 = rd4(Hs, i1, kq); s.x += a1.x; s.y += a1.y; s.z += a1.z; s.w += a1.w;
            float4 a2 = rd4(Hs, i2, kq); s.x += a2.x; s.y += a2.y; s.z += a2.z; s.w += a2.w;
            float4 a3 = rd4(Hs, i3, kq); s.x += a3.x; s.y += a3.y; s.z += a3.z; s.w += a3.w;
            float4 a4 = rd4(Hs, i4, kq); s.x += a4.x; s.y += a4.y; s.z += a4.z; s.w += a4.w;
            float4 a5 = rd4(Hs, i5, kq); s.x += a5.x; s.y += a5.y; s.z += a5.z; s.w += a5.w;
            const float4 bv = ((const float4*)bb)[kq];
            pkv[ps][j].x = (int)splitpack(fmaxf(s.x * S6 + bv.x, 0.0f));
            pkv[ps][j].y = (int)splitpack(fmaxf(s.y * S6 + bv.y, 0.0f));
            pkv[ps][j].z = (int)splitpack(fmaxf(s.z * S6 + bv.z, 0.0f));
            pkv[ps][j].w = (int)splitpack(fmaxf(s.w * S6 + bv.w, 0.0f));
          }
        }
      }
      __syncthreads();  // ALL reads (both passes) done before in-place writes
      unsigned* Hu = (unsigned*)Hs;
#pragma unroll
      for (int ps = 0; ps < 2; ps++) {
        const int row = 128 * ps + rs;
        if (row < NPG) {
          const int sw = row & 7;
#pragma unroll
          for (int j = 0; j < 2; j++) {
            const int kq = g0 + 8 * j + 16 * ph;
            *(int4*)(Hu + row * MD + ((kq ^ sw) << 2)) = pkv[ps][j];
          }
        }
      }
      __syncthreads();  // packed writes visible
    }

    // ---- MFMA: h_{l+1} = x @ W_{l+1} (split-bf16 3-product, c-outer) ----
    const unsigned short* Wh = WhiF + (size_t)l * 16384;
    const unsigned short* Wl_ = WloF + (size_t)l * 16384;
    floatx4 acc[7];
#pragma unroll
    for (int i = 0; i < 7; i++) acc[i] = (floatx4){0.f, 0.f, 0.f, 0.f};
    const int swm = m & 7;  // row&7 == m&7 (16*RT multiple of 8)
#pragma unroll
    for (int c = 0; c < 4; c++) {
      const size_t off = ((size_t)(Tc * 4 + c) * 64 + lane) * 8;
      short8 bhi = *(const short8*)(Wh + off);
      short8 blo = *(const short8*)(Wl_ + off);
      const int g1 = (2 * q + 8 * c) ^ swm;
      const int g2 = (2 * q + 8 * c + 1) ^ swm;
#pragma unroll
      for (int i = 0; i < 7; i++) {
        if (i < nrt) {
          // rows 200..207 read garbage: row-confined in MFMA, discarded
          const unsigned* base = (const unsigned*)Hs + (16 * (rt0 + i) + m) * MD;
          int4 u = *(const int4*)(base + (g1 << 2));
          int4 v = *(const int4*)(base + (g2 << 2));
          short8 ahi, alo;
          unpack8(u, v, &ahi, &alo);
          acc[i] = __builtin_amdgcn_mfma_f32_16x16x32_bf16(ahi, bhi, acc[i], 0, 0, 0);
          acc[i] = __builtin_amdgcn_mfma_f32_16x16x32_bf16(ahi, blo, acc[i], 0, 0, 0);
          acc[i] = __builtin_amdgcn_mfma_f32_16x16x32_bf16(alo, bhi, acc[i], 0, 0, 0);
        }
      }
    }
    __syncthreads();  // all packed-x frag reads done before overwrite

    // ---- write-back h_{l+1} (fp32, unified addressing) ----
    {
      const int colg = 4 * Tc + (m >> 2);  // (16*Tc+m)>>2
      const int cw = m & 3;
#pragma unroll
      for (int i = 0; i < 7; i++) {
        if (i < nrt) {
#pragma unroll
          for (int reg = 0; reg < 4; reg++) {
            const int row = 16 * (rt0 + i) + 4 * q + reg;
            if (row < NPG)
              Hs[row * MD + ((colg ^ (row & 7)) << 2) + cw] = acc[i][reg];
          }
        }
      }
    }
    __syncthreads();
  }

  // ---- tail: x3 = relu(S6*agg(h2) + b2), in place, same shape ----
  {
    const float* bb = convb + 2 * MD;
#pragma unroll 1
    for (int ph = 0; ph < 2; ph++) {
      float4 xv[2][2];  // 16 regs live across ONE barrier
#pragma unroll
      for (int ps = 0; ps < 2; ps++) {
        const int row = 128 * ps + rs;
        if (row < NPG) {
          const int* kn = kl + row * KNN;
          const int i1 = kn[0], i2 = kn[1], i3 = kn[2], i4 = kn[3], i5 = kn[4];
#pragma unroll
          for (int j = 0; j < 2; j++) {
            const int kq = g0 + 8 * j + 16 * ph;
            float4 s = rd4(Hs, row, kq);
            float4 a1 = rd4(Hs, i1, kq); s.x += a1.x; s.y += a1.y; s.z += a1.z; s.w += a1.w;
            float4 a2 = rd4(Hs, i2, kq); s.x += a2.x; s.y += a2.y; s.z += a2.z; s.w += a2.w;
            float4 a3 = rd4(Hs, i3, kq); s.x += a3.x; s.y += a3.y; s.z += a3.z; s.w += a3.w;
            float4 a4 = rd4(Hs, i4, kq); s.x += a4.x; s.y += a4.y; s.z += a4.z; s.w += a4.w;
            float4 a5 = rd4(Hs, i5, kq); s.x += a5.x; s.y += a5.y; s.z += a5.z; s.w += a5.w;
            const float4 bv = ((const float4*)bb)[kq];
            xv[ps][j].x = fmaxf(s.x * S6 + bv.x, 0.0f);
            xv[ps][j].y = fmaxf(s.y * S6 + bv.y, 0.0f);
            xv[ps][j].z = fmaxf(s.z * S6 + bv.z, 0.0f);
            xv[ps][j].w = fmaxf(s.w * S6 + bv.w, 0.0f);
          }
        }
      }
      __syncthreads();
#pragma unroll
      for (int ps = 0; ps < 2; ps++) {
        const int row = 128 * ps + rs;
        if (row < NPG) {
          const int sw = row & 7;
#pragma unroll
          for (int j = 0; j < 2; j++) {
            const int kq = g0 + 8 * j + 16 * ph;
            *(float4*)(Hs + row * MD + ((kq ^ sw) << 2)) = xv[ps][j];
          }
        }
      }
      __syncthreads();
    }
  }

  // ---- mean pool: 8 row-groups x 128 cols (unified addressing reads) ----
  {
    const int col = t & 127;
    const int j = t >> 7;  // 0..7, rows j*25..j*25+24
    const int colg = col >> 2, cw = col & 3;
    float s = 0.f;
    for (int i = 0; i < 25; i++) {
      const int row = j * 25 + i;
      s += Hs[row * MD + ((colg ^ (row & 7)) << 2) + cw];
    }
    red[j * MD + col] = s;
  }
  __syncthreads();
  if (t < MD) {
    float p = 0.f;
#pragma unroll
    for (int j = 0; j < 8; j++) p += red[j * MD + t];
    pooled[t] = p * (1.0f / (float)NPG);
  }
  __syncthreads();

  // ---- regressor MLP ----
  if (t < 64) {
    float a = rb1[t];
    for (int c = 0; c < 128; c++) a += pooled[c] * rW1[c * 64 + t];
    h1s[t] = fmaxf(a, 0.0f);
  }
  __syncthreads();
  if (t < 32) {
    float a = rb2[t];
    for (int c = 0; c < 64; c++) a += h1s[c] * rW2[c * 32 + t];
    h2s[t] = fmaxf(a, 0.0f);
  }
  __syncthreads();
  if (t == 0) {
    float a = rb3[0];
    for (int c = 0; c < 32; c++) a += h2s[c] * rW3[c];
    out[g] = a;
  }
}

extern "C" void kernel_launch(void* const* d_in, const int* in_sizes, int n_in,
                              void* d_out, int out_size, void* d_ws, size_t ws_size,
                              hipStream_t stream) {
  const int* z = (const int*)d_in[0];
  const float* pos = (const float*)d_in[1];
  const float* emb = (const float*)d_in[3];
  const float* convW = (const float*)d_in[4];  // [3][128][128]
  const float* convb = (const float*)d_in[5];  // [3][128]
  const float* rW1 = (const float*)d_in[6];
  const float* rb1 = (const float*)d_in[7];
  const float* rW2 = (const float*)d_in[8];
  const float* rb2 = (const float*)d_in[9];
  const float* rW3 = (const float*)d_in[10];
  const float* rb3 = (const float*)d_in[11];
  float* out = (float*)d_out;

  char* ws = (char*)d_ws;
  float* embW = (float*)ws;                                 // 51,200 B
  unsigned short* WhiF = (unsigned short*)(ws + 51200);     // 65,536 B
  unsigned short* WloF = WhiF + 32768;                      // 65,536 B

  emb_prepack_kernel<<<216, 256, 0, stream>>>(emb, convW, embW, WhiF, WloF);
  fused_kernel<<<NG, 1024, 0, stream>>>(z, pos, embW, convb, WhiF, WloF,
                                        rW1, rb1, rW2, rb2, rW3, rb3, out);
}